// Round 5
// baseline (118.611 us; speedup 1.0000x reference)
//
#include <hip/hip_runtime.h>
#include <hip/hip_bf16.h>
#include <math.h>

// TransitionLoss on MI355X (gfx950), v5 — two dispatches.
// K1: sim rows (2/block) + all 64 (target,sub)-pair masked row-stats fused,
//     + pair lists + meta. K2: one block per (pair,part): build X fp16 in LDS
//     (X[a,k]=exp(sim[a,ik]-q[k]-w[a])), Gram G=XX^T via MFMA from LDS,
//     loss terms relu(E[r]F[c]sqrt(G)-.2)/relu(.5-..), atomicAdd into out.
// Dedup: loss depends only on (target,sub) -> 64 pairs, weight = multiplicity.

constexpr int kB = 256;
constexpr int kD = 512;
constexpr float NEG_BIG = -3.4e38f;

typedef _Float16 f16x8 __attribute__((ext_vector_type(8)));
typedef float f32x16 __attribute__((ext_vector_type(16)));

// ws byte offsets
constexpr int O_SIM = 0;                  // 256*256 f32
constexpr int O_M   = 262144;             // [64][256] f32
constexpr int O_L   = 327680;             // [64][256] f32
constexpr int O_IDX = 393216;             // [64][4][256] u16
constexpr int O_CNT = 524288;             // [64][4] int
constexpr int O_MI  = 525312;             // [128] int4 {nR,nK,SKh,KP}
constexpr int O_MS  = 527360;             // [128] f32 scale (1/256 folded)

// K2 dynamic LDS layout (worst-case caps; bytes)
constexpr int XB_Q   = 135168;            // X cap: 256 rows x 264 halves
constexpr int XB_E   = XB_Q + 1024;
constexpr int XB_F   = XB_E + 1024;
constexpr int XB_IK  = XB_F + 1024;
constexpr int XB_IR  = XB_IK + 512;
constexpr int XB_ROW = XB_IR + 512;       // rowst[8][260] f32
constexpr int XB_RED = XB_ROW + 8320;
constexpr int K2_LDS = XB_RED + 32;       // 147648 <= 163840

// ---------------- K1: sim rows + stats + lists ----------------
__global__ __launch_bounds__(512)
void simStatsKernel(const float* __restrict__ f, const int* __restrict__ tgt,
                    const int* __restrict__ sub, float* __restrict__ sim,
                    float* __restrict__ Mv, float* __restrict__ Lv,
                    unsigned short* __restrict__ idxAll, int* __restrict__ cnt4,
                    int4* __restrict__ metaI, float* __restrict__ metaS,
                    float* __restrict__ out) {
  __shared__ float frow[2][512];
  __shared__ float panel[2][260];
  const int tid = threadIdx.x, lane = tid & 63, wave = tid >> 6;
  const int r0 = blockIdx.x * 2;
  if (tid < 256)
    ((float4*)frow)[tid] = ((const float4*)(f + (size_t)r0 * kD))[tid];
  __syncthreads();
  // thread-per-column dot: col = tid&255, row-half = tid>>8 (wave-uniform)
  {
    const int col = tid & 255, rh = tid >> 8;
    const float* fc = f + (size_t)col * kD;
    const float* fr = frow[rh];
    float acc = 0.f;
#pragma unroll 8
    for (int k = 0; k < kD; k += 4) {
      float4 b = *(const float4*)(fc + k);
      float4 a = *(const float4*)(fr + k);   // LDS broadcast (uniform addr/wave)
      acc = fmaf(a.x, b.x, acc); acc = fmaf(a.y, b.y, acc);
      acc = fmaf(a.z, b.z, acc); acc = fmaf(a.w, b.w, acc);
    }
    sim[(size_t)(r0 + rh) * kB + col] = acc;
    panel[rh][col] = acc;
  }
  __syncthreads();
  // stats: wave w -> row (w&1), pairs [16*(w>>1), +16). Mask for row a, pair
  // (t,s): cols with (tgt[c]==t)==(tgt[a]==t) && (sub[c]==s)!=(sub[a]==s).
  {
    const int row = wave & 1, a = r0 + row;
    const float4 v4 = ((const float4*)panel[row])[lane];
    const int4 t4 = ((const int4*)tgt)[lane];
    const int4 s4 = ((const int4*)sub)[lane];
    const int ta = tgt[a], sa = sub[a];
    const int p0 = (wave >> 1) * 16;
    for (int jj = 0; jj < 16; jj++) {
      const int p = p0 + jj, t = p >> 1, s = p & 1;
      const bool pa = (ta == t), ia = (sa == s);
      const bool e0 = ((t4.x == t) == pa) && ((s4.x == s) != ia);
      const bool e1 = ((t4.y == t) == pa) && ((s4.y == s) != ia);
      const bool e2 = ((t4.z == t) == pa) && ((s4.z == s) != ia);
      const bool e3 = ((t4.w == t) == pa) && ((s4.w == s) != ia);
      float m = fmaxf(fmaxf(e0 ? v4.x : NEG_BIG, e1 ? v4.y : NEG_BIG),
                      fmaxf(e2 ? v4.z : NEG_BIG, e3 ? v4.w : NEG_BIG));
#pragma unroll
      for (int o = 32; o >= 1; o >>= 1) m = fmaxf(m, __shfl_xor(m, o, 64));
      float ss = (e0 ? __expf(v4.x - m) : 0.f) + (e1 ? __expf(v4.y - m) : 0.f)
               + (e2 ? __expf(v4.z - m) : 0.f) + (e3 ? __expf(v4.w - m) : 0.f);
#pragma unroll
      for (int o = 32; o >= 1; o >>= 1) ss += __shfl_xor(ss, o, 64);
      if (lane == 0) { Mv[p * 256 + a] = m; Lv[p * 256 + a] = __logf(ss); }
    }
  }
  // lists + meta: blocks 0..63, wave 0 (pair = blockIdx.x)
  if (blockIdx.x < 64 && wave == 0) {
    const int p = blockIdx.x, t = p >> 1, s = p & 1;
    int base[4] = {0, 0, 0, 0};
    for (int chunk = 0; chunk < 4; chunk++) {
      int c = chunk * 64 + lane;
      bool pos = (tgt[c] == t), intra = (sub[c] == s);
      int cat = pos ? (intra ? 0 : 1) : (intra ? 2 : 3);  // mpi mpc mni mnc
#pragma unroll
      for (int l = 0; l < 4; l++) {
        bool fl = (cat == l);
        unsigned long long mm = __ballot(fl);
        if (fl) {
          int pf = __popcll(mm & ((1ull << lane) - 1ull));
          idxAll[(p * 4 + l) * 256 + base[l] + pf] = (unsigned short)c;
        }
        base[l] += __popcll(mm);
      }
    }
    if (lane == 0) {
      cnt4[p * 4 + 0] = base[0]; cnt4[p * 4 + 1] = base[1];
      cnt4[p * 4 + 2] = base[2]; cnt4[p * 4 + 3] = base[3];
      const int mult = base[0];   // anchors with this (t,s) pair
#pragma unroll
      for (int part = 0; part < 2; part++) {
        int nR = part ? base[0] : base[2];
        int nK = part ? base[1] : base[3];
        int KP = (nK + 15) & ~15;
        int4 mi; mi.x = nR; mi.y = nK; mi.z = KP + 8; mi.w = KP;
        metaI[p * 2 + part] = mi;
        metaS[p * 2 + part] = (mult > 0 && nR > 0 && nK > 0)
            ? (float)mult / ((float)nR * (float)nR * 256.f) : 0.f;
      }
    }
  }
  if (blockIdx.x == 64 && tid == 0) out[0] = 0.f;
}

// ---------------- K2: per-(pair,part) X build + Gram + eval ----------------
__global__ __launch_bounds__(512)
void pairKernel(const float* __restrict__ sim, const float* __restrict__ Mv,
                const float* __restrict__ Lv, const unsigned short* __restrict__ idxAll,
                const int* __restrict__ cnt4, const int4* __restrict__ metaI,
                const float* __restrict__ metaS, float* __restrict__ out) {
  extern __shared__ char smemRaw[];
  const int pp = blockIdx.x, p = pp >> 1, part = pp & 1;
  const int tid = threadIdx.x, lane = tid & 63, wave = tid >> 6;
  const float scale = metaS[pp];
  if (scale == 0.f) {
    // pos part with nonempty R but empty K: tr=0 -> x=1e-6 -> (0.5-1e-6) each
    if (part == 1 && tid == 0) {
      int nR = cnt4[p * 4 + 0], nK = cnt4[p * 4 + 1];
      if (nR > 0 && nK == 0)
        atomicAdd(out, (float)nR * (0.5f - 1e-6f) * (1.f / 256.f));
    }
    return;
  }
  const int4 mi = metaI[pp];
  const int nR = mi.x, nK = mi.y, SKh = mi.z, KP = mi.w;
  const int nT = (nR + 31) >> 5, nRp = nT << 5;

  _Float16* Xh = (_Float16*)smemRaw;
  float* q   = (float*)(smemRaw + XB_Q);
  float* Ev  = (float*)(smemRaw + XB_E);
  float* Fv  = (float*)(smemRaw + XB_F);
  unsigned short* iKs = (unsigned short*)(smemRaw + XB_IK);
  unsigned short* iRs = (unsigned short*)(smemRaw + XB_IR);
  float* rowst = (float*)(smemRaw + XB_ROW);   // [8][260]
  float* wred  = (float*)(smemRaw + XB_RED);

  const unsigned short* giR = idxAll + (p * 4 + (part ? 0 : 2)) * 256;
  const unsigned short* giK = idxAll + (p * 4 + (part ? 1 : 3)) * 256;
  if (tid < 256) {
    iRs[tid] = (tid < nR) ? giR[tid] : (unsigned short)0;
    int ik = (tid < nK) ? (int)giK[tid] : 0;
    iKs[tid] = (unsigned short)ik;
    q[tid] = (tid < nK) ? 0.5f * (Mv[p * 256 + ik] + Lv[p * 256 + ik]) : 0.f;
  }
  __syncthreads();

  // build X rows (wave-local staging; no block barriers; next-row prefetch)
  auto loadRow = [&](int r) -> float4 {
    if (r < nR)
      return ((const float4*)(sim + (size_t)iRs[r] * kB))[lane];
    float4 z; z.x = z.y = z.z = z.w = 0.f; return z;
  };
  float4 v = loadRow(wave);
  for (int r = wave; r < nRp; r += 8) {
    float4 vn = loadRow(r + 8);
    if (r < nR) {
      *(float4*)(rowst + wave * 260 + lane * 4) = v;
      asm volatile("s_waitcnt lgkmcnt(0)" ::: "memory");  // wave-local RAW
      float vals[4];
      float w = NEG_BIG;
#pragma unroll
      for (int j = 0; j < 4; j++) {
        int k = lane + 64 * j;
        float x = NEG_BIG;
        if (k < nK) x = rowst[wave * 260 + (int)iKs[k]] - q[k];
        vals[j] = x; w = fmaxf(w, x);
      }
#pragma unroll
      for (int o = 32; o >= 1; o >>= 1) w = fmaxf(w, __shfl_xor(w, o, 64));
#pragma unroll
      for (int j = 0; j < 4; j++) {
        int k = lane + 64 * j;
        if (k < KP) Xh[r * SKh + k] = (_Float16)__expf(vals[j] - w);  // pad->0
      }
      if (lane == 0) {
        float u = Mv[p * 256 + (int)iRs[r]] + Lv[p * 256 + (int)iRs[r]];
        Ev[r] = __expf(0.5f * (w - u));
        Fv[r] = __expf(0.5f * w);
      }
    } else {  // zero pad rows [nR, nRp)
#pragma unroll
      for (int j = 0; j < 4; j++) {
        int k = lane + 64 * j;
        if (k < KP) Xh[r * SKh + k] = (_Float16)0.f;
      }
      if (lane == 0) { Ev[r] = 0.f; Fv[r] = 0.f; }
    }
    v = vn;
  }
  __syncthreads();

  // Gram tiles (32x32) via MFMA from LDS + eval
  float res = 0.f;
  const int l31 = lane & 31, kg = lane >> 5;
  const int nTiles = nT * nT;
  for (int t = wave; t < nTiles; t += 8) {
    const int r0t = (t / nT) << 5, c0t = (t % nT) << 5;
    const _Float16* pa = Xh + (r0t + l31) * SKh + 8 * kg;
    const _Float16* pb = Xh + (c0t + l31) * SKh + 8 * kg;
    f32x16 acc;
#pragma unroll
    for (int g = 0; g < 16; g++) acc[g] = 0.f;
    for (int kb = 0; kb < KP; kb += 16) {
      f16x8 av = *(const f16x8*)(pa + kb);
      f16x8 bv = *(const f16x8*)(pb + kb);
      acc = __builtin_amdgcn_mfma_f32_32x32x16_f16(av, bv, acc, 0, 0, 0);
    }
    const int c = c0t + l31;
    if (c < nR) {
      const float Fc = Fv[c];
      const int rb = r0t + 4 * kg;
#pragma unroll
      for (int g = 0; g < 16; g++) {
        const int r = rb + (g & 3) + ((g >> 2) << 3);  // C/D: col=lane&31
        if (r < nR) {
          float x = Ev[r] * Fc * sqrtf(acc[g]);  // sqrt(tr), exact factorization
          x = fmaxf(x, 1e-6f);                   // tr clip 1e-12
          res += part ? fmaxf(0.5f - x, 0.f) : fmaxf(x - 0.2f, 0.f);
        }
      }
    }
  }
#pragma unroll
  for (int o = 32; o >= 1; o >>= 1) res += __shfl_xor(res, o, 64);
  if (lane == 0) wred[wave] = res;
  __syncthreads();
  if (tid == 0) {
    float tot = 0.f;
#pragma unroll
    for (int w2 = 0; w2 < 8; w2++) tot += wred[w2];
    atomicAdd(out, tot * scale);
  }
}

extern "C" void kernel_launch(void* const* d_in, const int* in_sizes, int n_in,
                              void* d_out, int out_size, void* d_ws, size_t ws_size,
                              hipStream_t stream) {
  (void)in_sizes; (void)n_in; (void)out_size; (void)ws_size;
  const float* feature = (const float*)d_in[0];
  const int* subv = (const int*)d_in[1];
  const int* tgtv = (const int*)d_in[2];
  float* out = (float*)d_out;
  char* ws = (char*)d_ws;

  float* sim = (float*)(ws + O_SIM);
  float* Mv = (float*)(ws + O_M);
  float* Lv = (float*)(ws + O_L);
  unsigned short* idxAll = (unsigned short*)(ws + O_IDX);
  int* cnt4 = (int*)(ws + O_CNT);
  int4* metaI = (int4*)(ws + O_MI);
  float* metaS = (float*)(ws + O_MS);

  (void)hipFuncSetAttribute(reinterpret_cast<const void*>(pairKernel),
                            hipFuncAttributeMaxDynamicSharedMemorySize, K2_LDS);

  simStatsKernel<<<128, 512, 0, stream>>>(feature, tgtv, subv, sim, Mv, Lv,
                                          idxAll, cnt4, metaI, metaS, out);
  pairKernel<<<128, 512, K2_LDS, stream>>>(sim, Mv, Lv, idxAll, cnt4,
                                           metaI, metaS, out);
}

// Round 6
// 107.161 us; speedup vs baseline: 1.1069x; 1.1069x over previous
//
#include <hip/hip_runtime.h>
#include <hip/hip_bf16.h>
#include <math.h>

// TransitionLoss on MI355X (gfx950), v6 — two dispatches.
// K1: 2 sim rows/block via wave-split-K coalesced dots (anchor slice in regs),
//     + all 64 (target,sub)-pair masked row-stats + pair lists + meta.
// K2: one block per (pair,part): X fp16 in LDS, Gram G=XX^T via MFMA,
//     loss relu(E[r]F[c]sqrt(G)-.2)/relu(.5-..), atomicAdd into out.
// Dedup: loss depends only on (target,sub) -> 64 pairs, weight = multiplicity.

constexpr int kB = 256;
constexpr int kD = 512;
constexpr float NEG_BIG = -3.4e38f;

typedef _Float16 f16x8 __attribute__((ext_vector_type(8)));
typedef float f32x16 __attribute__((ext_vector_type(16)));

// ws byte offsets
constexpr int O_SIM = 0;                  // 256*256 f32
constexpr int O_M   = 262144;             // [64][256] f32
constexpr int O_L   = 327680;             // [64][256] f32
constexpr int O_IDX = 393216;             // [64][4][256] u16
constexpr int O_CNT = 524288;             // [64][4] int
constexpr int O_MI  = 525312;             // [128] int4 {nR,nK,SKh,KP}
constexpr int O_MS  = 527360;             // [128] f32 scale (1/256 folded)

// K2 dynamic LDS layout (true worst case: nR+nK<=256 -> X <= 160x136 halves)
constexpr int XB_Q   = 43520;             // X cap bytes
constexpr int XB_E   = XB_Q + 1024;      // q then Ev/Fv
constexpr int XB_F   = XB_E + 1024;
constexpr int XB_IK  = XB_F + 1024;
constexpr int XB_IR  = XB_IK + 512;
constexpr int XB_ROW = XB_IR + 512;       // rowst[8][260] f32 (47616, 16-aligned)
constexpr int XB_RED = XB_ROW + 8320;
constexpr int K2_LDS = XB_RED + 32;       // 55968 <= 65536

// ---------------- K1: sim rows (coalesced) + stats + lists ----------------
__global__ __launch_bounds__(512)
void simStatsKernel(const float* __restrict__ f, const int* __restrict__ tgt,
                    const int* __restrict__ sub, float* __restrict__ sim,
                    float* __restrict__ Mv, float* __restrict__ Lv,
                    unsigned short* __restrict__ idxAll, int* __restrict__ cnt4,
                    int4* __restrict__ metaI, float* __restrict__ metaS,
                    float* __restrict__ out) {
  __shared__ float frow[2][512];
  __shared__ float panel[2][260];
  const int tid = threadIdx.x, lane = tid & 63, wave = tid >> 6;
  const int r0 = blockIdx.x * 2;
  if (tid < 256)
    ((float4*)frow)[tid] = ((const float4*)(f + (size_t)r0 * kD))[tid];
  __syncthreads();
  {
    // anchor-row k-slice in registers: read LDS exactly once per wave
    const float4 a00 = *(const float4*)&frow[0][lane * 8];
    const float4 a01 = *(const float4*)&frow[0][lane * 8 + 4];
    const float4 a10 = *(const float4*)&frow[1][lane * 8];
    const float4 a11 = *(const float4*)&frow[1][lane * 8 + 4];
#pragma unroll 4
    for (int j = 0; j < 32; j++) {
      const int c = (wave << 5) | j;
      const float* fc = f + (size_t)c * kD + lane * 8;   // lane-contiguous
      const float4 b0 = *(const float4*)fc;
      const float4 b1 = *(const float4*)(fc + 4);
      float d0 = 0.f, d1 = 0.f;
      d0 = fmaf(a00.x, b0.x, d0); d1 = fmaf(a10.x, b0.x, d1);
      d0 = fmaf(a00.y, b0.y, d0); d1 = fmaf(a10.y, b0.y, d1);
      d0 = fmaf(a00.z, b0.z, d0); d1 = fmaf(a10.z, b0.z, d1);
      d0 = fmaf(a00.w, b0.w, d0); d1 = fmaf(a10.w, b0.w, d1);
      d0 = fmaf(a01.x, b1.x, d0); d1 = fmaf(a11.x, b1.x, d1);
      d0 = fmaf(a01.y, b1.y, d0); d1 = fmaf(a11.y, b1.y, d1);
      d0 = fmaf(a01.z, b1.z, d0); d1 = fmaf(a11.z, b1.z, d1);
      d0 = fmaf(a01.w, b1.w, d0); d1 = fmaf(a11.w, b1.w, d1);
#pragma unroll
      for (int o = 32; o >= 1; o >>= 1) {        // interleaved dual reduce
        d0 += __shfl_xor(d0, o, 64);
        d1 += __shfl_xor(d1, o, 64);
      }
      if (lane == 0) { panel[0][c] = d0; panel[1][c] = d1; }
    }
  }
  __syncthreads();
  if (tid < 128) {   // coalesced sim write from panel
    int rh = tid >> 6, t6 = tid & 63;
    ((float4*)(sim + (size_t)(r0 + rh) * kB))[t6] = ((const float4*)panel[rh])[t6];
  }
  // stats: wave w -> row (w&1), pairs [16*(w>>1), +16). Mask for row a, pair
  // (t,s): cols with (tgt[c]==t)==(tgt[a]==t) && (sub[c]==s)!=(sub[a]==s).
  {
    const int row = wave & 1, a = r0 + row;
    const float4 v4 = ((const float4*)panel[row])[lane];
    const int4 t4 = ((const int4*)tgt)[lane];
    const int4 s4 = ((const int4*)sub)[lane];
    const int ta = tgt[a], sa = sub[a];
    const int p0 = (wave >> 1) * 16;
    for (int jj = 0; jj < 16; jj++) {
      const int p = p0 + jj, t = p >> 1, s = p & 1;
      const bool pa = (ta == t), ia = (sa == s);
      const bool e0 = ((t4.x == t) == pa) && ((s4.x == s) != ia);
      const bool e1 = ((t4.y == t) == pa) && ((s4.y == s) != ia);
      const bool e2 = ((t4.z == t) == pa) && ((s4.z == s) != ia);
      const bool e3 = ((t4.w == t) == pa) && ((s4.w == s) != ia);
      float m = fmaxf(fmaxf(e0 ? v4.x : NEG_BIG, e1 ? v4.y : NEG_BIG),
                      fmaxf(e2 ? v4.z : NEG_BIG, e3 ? v4.w : NEG_BIG));
#pragma unroll
      for (int o = 32; o >= 1; o >>= 1) m = fmaxf(m, __shfl_xor(m, o, 64));
      float ss = (e0 ? __expf(v4.x - m) : 0.f) + (e1 ? __expf(v4.y - m) : 0.f)
               + (e2 ? __expf(v4.z - m) : 0.f) + (e3 ? __expf(v4.w - m) : 0.f);
#pragma unroll
      for (int o = 32; o >= 1; o >>= 1) ss += __shfl_xor(ss, o, 64);
      if (lane == 0) { Mv[p * 256 + a] = m; Lv[p * 256 + a] = __logf(ss); }
    }
  }
  // lists + meta: blocks 0..63, wave 0 (pair = blockIdx.x)
  if (blockIdx.x < 64 && wave == 0) {
    const int p = blockIdx.x, t = p >> 1, s = p & 1;
    int base[4] = {0, 0, 0, 0};
    for (int chunk = 0; chunk < 4; chunk++) {
      int c = chunk * 64 + lane;
      bool pos = (tgt[c] == t), intra = (sub[c] == s);
      int cat = pos ? (intra ? 0 : 1) : (intra ? 2 : 3);  // mpi mpc mni mnc
#pragma unroll
      for (int l = 0; l < 4; l++) {
        bool fl = (cat == l);
        unsigned long long mm = __ballot(fl);
        if (fl) {
          int pf = __popcll(mm & ((1ull << lane) - 1ull));
          idxAll[(p * 4 + l) * 256 + base[l] + pf] = (unsigned short)c;
        }
        base[l] += __popcll(mm);
      }
    }
    if (lane == 0) {
      cnt4[p * 4 + 0] = base[0]; cnt4[p * 4 + 1] = base[1];
      cnt4[p * 4 + 2] = base[2]; cnt4[p * 4 + 3] = base[3];
      const int mult = base[0];   // anchors with this (t,s) pair
#pragma unroll
      for (int part = 0; part < 2; part++) {
        int nR = part ? base[0] : base[2];
        int nK = part ? base[1] : base[3];
        int KP = (nK + 15) & ~15;
        int4 mi; mi.x = nR; mi.y = nK; mi.z = KP + 8; mi.w = KP;
        metaI[p * 2 + part] = mi;
        metaS[p * 2 + part] = (mult > 0 && nR > 0 && nK > 0)
            ? (float)mult / ((float)nR * (float)nR * 256.f) : 0.f;
      }
    }
  }
  if (blockIdx.x == 64 && tid == 0) out[0] = 0.f;
}

// ---------------- K2: per-(pair,part) X build + Gram + eval ----------------
__global__ __launch_bounds__(512)
void pairKernel(const float* __restrict__ sim, const float* __restrict__ Mv,
                const float* __restrict__ Lv, const unsigned short* __restrict__ idxAll,
                const int* __restrict__ cnt4, const int4* __restrict__ metaI,
                const float* __restrict__ metaS, float* __restrict__ out) {
  extern __shared__ char smemRaw[];
  const int pp = blockIdx.x, p = pp >> 1, part = pp & 1;
  const int tid = threadIdx.x, lane = tid & 63, wave = tid >> 6;
  const float scale = metaS[pp];
  if (scale == 0.f) {
    // pos part with nonempty R but empty K: tr=0 -> x=1e-6 -> (0.5-1e-6) each
    if (part == 1 && tid == 0) {
      int nR = cnt4[p * 4 + 0], nK = cnt4[p * 4 + 1];
      if (nR > 0 && nK == 0)
        atomicAdd(out, (float)nR * (0.5f - 1e-6f) * (1.f / 256.f));
    }
    return;
  }
  const int4 mi = metaI[pp];
  const int nR = mi.x, nK = mi.y, SKh = mi.z, KP = mi.w;
  const int nT = (nR + 31) >> 5, nRp = nT << 5;

  _Float16* Xh = (_Float16*)smemRaw;
  float* q   = (float*)(smemRaw + XB_Q);
  float* Ev  = (float*)(smemRaw + XB_E);
  float* Fv  = (float*)(smemRaw + XB_F);
  unsigned short* iKs = (unsigned short*)(smemRaw + XB_IK);
  unsigned short* iRs = (unsigned short*)(smemRaw + XB_IR);
  float* rowst = (float*)(smemRaw + XB_ROW);   // [8][260]
  float* wred  = (float*)(smemRaw + XB_RED);

  const unsigned short* giR = idxAll + (p * 4 + (part ? 0 : 2)) * 256;
  const unsigned short* giK = idxAll + (p * 4 + (part ? 1 : 3)) * 256;
  if (tid < 256) {
    iRs[tid] = (tid < nR) ? giR[tid] : (unsigned short)0;
    int ik = (tid < nK) ? (int)giK[tid] : 0;
    iKs[tid] = (unsigned short)ik;
    q[tid] = (tid < nK) ? 0.5f * (Mv[p * 256 + ik] + Lv[p * 256 + ik]) : 0.f;
  }
  __syncthreads();

  // build X rows (wave-local staging; no block barriers; next-row prefetch)
  auto loadRow = [&](int r) -> float4 {
    if (r < nR)
      return ((const float4*)(sim + (size_t)iRs[r] * kB))[lane];
    float4 z; z.x = z.y = z.z = z.w = 0.f; return z;
  };
  float4 v = loadRow(wave);
  for (int r = wave; r < nRp; r += 8) {
    float4 vn = loadRow(r + 8);
    if (r < nR) {
      *(float4*)(rowst + wave * 260 + lane * 4) = v;
      asm volatile("s_waitcnt lgkmcnt(0)" ::: "memory");  // wave-local RAW
      float vals[4];
      float w = NEG_BIG;
#pragma unroll
      for (int j = 0; j < 4; j++) {
        int k = lane + 64 * j;
        float x = NEG_BIG;
        if (k < nK) x = rowst[wave * 260 + (int)iKs[k]] - q[k];
        vals[j] = x; w = fmaxf(w, x);
      }
#pragma unroll
      for (int o = 32; o >= 1; o >>= 1) w = fmaxf(w, __shfl_xor(w, o, 64));
#pragma unroll
      for (int j = 0; j < 4; j++) {
        int k = lane + 64 * j;
        if (k < KP) Xh[r * SKh + k] = (_Float16)__expf(vals[j] - w);  // pad->0
      }
      if (lane == 0) {
        float u = Mv[p * 256 + (int)iRs[r]] + Lv[p * 256 + (int)iRs[r]];
        Ev[r] = __expf(0.5f * (w - u));
        Fv[r] = __expf(0.5f * w);
      }
    } else {  // zero pad rows [nR, nRp)
#pragma unroll
      for (int j = 0; j < 4; j++) {
        int k = lane + 64 * j;
        if (k < KP) Xh[r * SKh + k] = (_Float16)0.f;
      }
      if (lane == 0) { Ev[r] = 0.f; Fv[r] = 0.f; }
    }
    v = vn;
  }
  __syncthreads();

  // Gram tiles (32x32) via MFMA from LDS + eval
  float res = 0.f;
  const int l31 = lane & 31, kg = lane >> 5;
  const int nTiles = nT * nT;
  for (int t = wave; t < nTiles; t += 8) {
    const int r0t = (t / nT) << 5, c0t = (t % nT) << 5;
    const _Float16* pa = Xh + (r0t + l31) * SKh + 8 * kg;
    const _Float16* pb = Xh + (c0t + l31) * SKh + 8 * kg;
    f32x16 acc;
#pragma unroll
    for (int g = 0; g < 16; g++) acc[g] = 0.f;
    for (int kb = 0; kb < KP; kb += 16) {
      f16x8 av = *(const f16x8*)(pa + kb);
      f16x8 bv = *(const f16x8*)(pb + kb);
      acc = __builtin_amdgcn_mfma_f32_32x32x16_f16(av, bv, acc, 0, 0, 0);
    }
    const int c = c0t + l31;
    if (c < nR) {
      const float Fc = Fv[c];
      const int rb = r0t + 4 * kg;
#pragma unroll
      for (int g = 0; g < 16; g++) {
        const int r = rb + (g & 3) + ((g >> 2) << 3);  // C/D: col=lane&31
        if (r < nR) {
          float x = Ev[r] * Fc * sqrtf(acc[g]);  // sqrt(tr), exact factorization
          x = fmaxf(x, 1e-6f);                   // tr clip 1e-12
          res += part ? fmaxf(0.5f - x, 0.f) : fmaxf(x - 0.2f, 0.f);
        }
      }
    }
  }
#pragma unroll
  for (int o = 32; o >= 1; o >>= 1) res += __shfl_xor(res, o, 64);
  if (lane == 0) wred[wave] = res;
  __syncthreads();
  if (tid == 0) {
    float tot = 0.f;
#pragma unroll
    for (int w2 = 0; w2 < 8; w2++) tot += wred[w2];
    atomicAdd(out, tot * scale);
  }
}

extern "C" void kernel_launch(void* const* d_in, const int* in_sizes, int n_in,
                              void* d_out, int out_size, void* d_ws, size_t ws_size,
                              hipStream_t stream) {
  (void)in_sizes; (void)n_in; (void)out_size; (void)ws_size;
  const float* feature = (const float*)d_in[0];
  const int* subv = (const int*)d_in[1];
  const int* tgtv = (const int*)d_in[2];
  float* out = (float*)d_out;
  char* ws = (char*)d_ws;

  float* sim = (float*)(ws + O_SIM);
  float* Mv = (float*)(ws + O_M);
  float* Lv = (float*)(ws + O_L);
  unsigned short* idxAll = (unsigned short*)(ws + O_IDX);
  int* cnt4 = (int*)(ws + O_CNT);
  int4* metaI = (int4*)(ws + O_MI);
  float* metaS = (float*)(ws + O_MS);

  simStatsKernel<<<128, 512, 0, stream>>>(feature, tgtv, subv, sim, Mv, Lv,
                                          idxAll, cnt4, metaI, metaS, out);
  pairKernel<<<128, 512, K2_LDS, stream>>>(sim, Mv, Lv, idxAll, cnt4,
                                           metaI, metaS, out);
}